// Round 7
// baseline (337.366 us; speedup 1.0000x reference)
//
#include <hip/hip_runtime.h>

#define N_NODES 50000
#define N_EDGES 800000
#define SCAN_BLOCKS 196          // ceil(50000/256)
#define WIN 6250                 // dst window per XCD group (50000/8)

typedef __attribute__((ext_vector_type(8))) short short8;
typedef __attribute__((ext_vector_type(4))) float f32x4;
typedef unsigned short ushort_t;
typedef unsigned int uint_t;

// ---------------- helpers ----------------
__device__ inline ushort_t f2bf(float f) {
    union { float f; uint_t u; } v; v.f = f;
    uint_t u = v.u;
    u += 0x7fffu + ((u >> 16) & 1u);   // RNE
    return (ushort_t)(u >> 16);
}
__device__ inline float bflo(uint_t v) { return __uint_as_float(v << 16); }
__device__ inline float bfhi(uint_t v) { return __uint_as_float(v & 0xffff0000u); }
__device__ inline uint_t packbf(float a, float b) {
    return (uint_t)f2bf(a) | ((uint_t)f2bf(b) << 16);
}

// ---------------- prep: cvt x->bf16, pack 3 weight sets, zero cnt ----------------
__global__ void prep(const float* __restrict__ x, uint_t* __restrict__ x_bf_u,
                     const float* __restrict__ Wl0, const float* __restrict__ Wr0,
                     const float* __restrict__ Wl1, const float* __restrict__ Wr1,
                     const float* __restrict__ Wl2, const float* __restrict__ Wr2,
                     ushort_t* __restrict__ pk0, ushort_t* __restrict__ pk1,
                     ushort_t* __restrict__ pkz, int* __restrict__ cnt) {
    int b = blockIdx.x, tid = threadIdx.x;
    if (b < 6250) {                                    // cvt: 1.6M ushort4
        int i = b * 256 + tid;
        float4 v = ((const float4*)x)[i];
        x_bf_u[i * 2] = packbf(v.x, v.y);
        x_bf_u[i * 2 + 1] = packbf(v.z, v.w);
    } else if (b < 6506) {                             // pack pk0 / pk1 (32768 each)
        int bb = b - 6250;
        const float* Wl = (bb < 128) ? Wl0 : Wl1;
        const float* Wr = (bb < 128) ? Wr0 : Wr1;
        ushort_t* out = (bb < 128) ? pk0 : pk1;
        int idx = (bb & 127) * 256 + tid;
        int j = idx & 7, l = (idx >> 3) & 63, t = (idx >> 9) & 7, ks = idx >> 12;
        int n = t * 16 + (l & 15);
        int k = ks * 32 + (l >> 4) * 8 + j;
        float w = (k < 128) ? Wl[k * 128 + n] : Wr[(k - 128) * 128 + n];
        out[idx] = f2bf(w);
    } else if (b < 6570) {                             // pack pkz (16384)
        int idx = (b - 6506) * 256 + tid;
        int j = idx & 7, l = (idx >> 3) & 63, t = (idx >> 9) & 7, ks = idx >> 12;
        int n = t * 16 + (l & 15);
        int k = ks * 32 + (l >> 4) * 8 + j;
        float w = (n < 64) ? Wl2[k * 64 + n] : Wr2[k * 64 + (n - 64)];
        pkz[idx] = f2bf(w);
    } else {                                           // zero cnt: 12500 int4
        int i = (b - 6570) * 256 + tid;
        if (i < 12500) ((int4*)cnt)[i] = make_int4(0, 0, 0, 0);
    }
}

// ---------------- CSR build: XCD-windowed counting sort ----------------
__global__ void count_edges_mp(const int* __restrict__ ei, int* __restrict__ cnt) {
    int g = blockIdx.x & 7;
    int nb = gridDim.x >> 3;
    int bi = blockIdx.x >> 3;
    int lo = g * WIN;
    for (int e = bi * 256 + threadIdx.x; e < N_EDGES; e += nb * 256) {
        int d = ei[N_EDGES + e];
        if ((unsigned)(d - lo) < WIN) atomicAdd(&cnt[d], 1);
    }
}

__global__ void fill_csr_mp(const int* __restrict__ ei, int* __restrict__ cursor,
                            int* __restrict__ csr_src) {
    int g = blockIdx.x & 7;
    int nb = gridDim.x >> 3;
    int bi = blockIdx.x >> 3;
    int lo = g * WIN;
    for (int e = bi * 256 + threadIdx.x; e < N_EDGES; e += nb * 256) {
        int d = ei[N_EDGES + e];
        if ((unsigned)(d - lo) < WIN) {
            int p = atomicAdd(&cursor[d], 1);
            csr_src[p] = ei[e];
        }
    }
}

// ---------------- one-kernel exclusive scan ----------------
__global__ void scan_all(const int* __restrict__ cnt, int* __restrict__ rowstart,
                         int* __restrict__ cursor) {
    __shared__ int s[256];
    __shared__ int wsum[4];
    int t = threadIdx.x, b = blockIdx.x;
    int base = b * 256;
    int pre = 0;
    for (int i = t; i < base; i += 256) pre += cnt[i];
    for (int off = 32; off; off >>= 1) pre += __shfl_down(pre, off, 64);
    if ((t & 63) == 0) wsum[t >> 6] = pre;
    __syncthreads();
    int prefix_base = wsum[0] + wsum[1] + wsum[2] + wsum[3];
    int i = base + t;
    int v = (i < N_NODES) ? cnt[i] : 0;
    s[t] = v;
    __syncthreads();
    for (int off = 1; off < 256; off <<= 1) {
        int add = (t >= off) ? s[t - off] : 0;
        __syncthreads();
        s[t] += add;
        __syncthreads();
    }
    int excl = s[t] - v + prefix_base;
    if (i < N_NODES) { rowstart[i] = excl; cursor[i] = excl; }
    if (b == 0 && t == 0) rowstart[N_NODES] = N_EDGES;
}

// ---------------- fat gather: 128-dim rows, uint4/lane, 4 edges per load ----------------
// chunk = lane&15 (16 uint4 = 256B row), esel = lane>>4 picks edge in group of 4.
// After loop: xor-reduce over esel (16,32); every lane holds dims (lane&15)*8..+7.
__device__ inline void gather_mean4_128(const uint4* __restrict__ base,
                                        const int* __restrict__ rowstart,
                                        const int* __restrict__ csr,
                                        int node, int lane, float* acc) {
    int s0 = rowstart[node], s1 = rowstart[node + 1];
    #pragma unroll
    for (int k = 0; k < 8; ++k) acc[k] = 0.f;
    int chunk = lane & 15, esel = lane >> 4;
    for (int b = s0; b < s1; b += 64) {
        int m = min(64, s1 - b);
        int idx = (lane < m) ? csr[b + lane] : 0;
        int j = 0;
        for (; j + 16 <= m; j += 16) {
            int i0 = __shfl(idx, j + esel, 64);
            int i1 = __shfl(idx, j + 4 + esel, 64);
            int i2 = __shfl(idx, j + 8 + esel, 64);
            int i3 = __shfl(idx, j + 12 + esel, 64);
            uint4 v0 = base[(size_t)i0 * 16 + chunk];
            uint4 v1 = base[(size_t)i1 * 16 + chunk];
            uint4 v2 = base[(size_t)i2 * 16 + chunk];
            uint4 v3 = base[(size_t)i3 * 16 + chunk];
            acc[0] += (bflo(v0.x) + bflo(v1.x)) + (bflo(v2.x) + bflo(v3.x));
            acc[1] += (bfhi(v0.x) + bfhi(v1.x)) + (bfhi(v2.x) + bfhi(v3.x));
            acc[2] += (bflo(v0.y) + bflo(v1.y)) + (bflo(v2.y) + bflo(v3.y));
            acc[3] += (bfhi(v0.y) + bfhi(v1.y)) + (bfhi(v2.y) + bfhi(v3.y));
            acc[4] += (bflo(v0.z) + bflo(v1.z)) + (bflo(v2.z) + bflo(v3.z));
            acc[5] += (bfhi(v0.z) + bfhi(v1.z)) + (bfhi(v2.z) + bfhi(v3.z));
            acc[6] += (bflo(v0.w) + bflo(v1.w)) + (bflo(v2.w) + bflo(v3.w));
            acc[7] += (bfhi(v0.w) + bfhi(v1.w)) + (bfhi(v2.w) + bfhi(v3.w));
        }
        for (; j < m; j += 4) {
            int e = j + esel;
            int s = __shfl(idx, min(e, m - 1), 64);
            if (e < m) {
                uint4 v = base[(size_t)s * 16 + chunk];
                acc[0] += bflo(v.x); acc[1] += bfhi(v.x);
                acc[2] += bflo(v.y); acc[3] += bfhi(v.y);
                acc[4] += bflo(v.z); acc[5] += bfhi(v.z);
                acc[6] += bflo(v.w); acc[7] += bfhi(v.w);
            }
        }
    }
    float inv = 1.0f / fmaxf((float)(s1 - s0), 1.0f);
    #pragma unroll
    for (int k = 0; k < 8; ++k) {
        acc[k] += __shfl_xor(acc[k], 16, 64);
        acc[k] += __shfl_xor(acc[k], 32, 64);
        acc[k] *= inv;
    }
}

// ---------------- fused layer: 16 nodes/block, 8 waves, 2 nodes/wave ----------------
// gather: wave w fills A-tile rows 2w, 2w+1. MFMA: wave w computes col-tile t=w.
// CHAIN: h2 = relu(gemm1) kept in LDS, chained into gemm2 -> [z|r].
template <bool CHAIN>
__global__ __launch_bounds__(512, 8) void layer_fused(
    const uint4* __restrict__ gsrc, const ushort_t* __restrict__ root,
    const int* __restrict__ rowstart, const int* __restrict__ csr_src,
    const ushort_t* __restrict__ Bpk, const float* __restrict__ bias1,
    const ushort_t* __restrict__ Bpkz, const float* __restrict__ bias2,
    ushort_t* __restrict__ h_out,
    ushort_t* __restrict__ z_bf, float* __restrict__ r_f32) {
    __shared__ __align__(16) ushort_t At[16 * 136];
    int lane = threadIdx.x & 63, wave = threadIdx.x >> 6;
    int nodeBase = blockIdx.x * 16;
    int chunk = lane & 15;

    #pragma unroll
    for (int i = 0; i < 2; ++i) {
        int m = wave * 2 + i;
        int node = nodeBase + m;
        float acc[8];
        #pragma unroll
        for (int k = 0; k < 8; ++k) acc[k] = 0.f;
        if (node < N_NODES) gather_mean4_128(gsrc, rowstart, csr_src, node, lane, acc);
        if (lane < 16) {
            uint4 w;
            w.x = packbf(acc[0], acc[1]); w.y = packbf(acc[2], acc[3]);
            w.z = packbf(acc[4], acc[5]); w.w = packbf(acc[6], acc[7]);
            *(uint4*)&At[m * 136 + chunk * 8] = w;
        }
    }
    __syncthreads();

    int row16 = lane & 15, quad = lane >> 4;
    const short8* bp = (const short8*)Bpk + lane;
    int rootRow = min(nodeBase + row16, N_NODES - 1);
    const ushort_t* rrow = root + (size_t)rootRow * 128;

    f32x4 acc1 = {0.f, 0.f, 0.f, 0.f};
    #pragma unroll
    for (int ks = 0; ks < 8; ++ks) {
        short8 afrag;
        if (ks < 4) afrag = *(const short8*)&At[row16 * 136 + ks * 32 + quad * 8];
        else        afrag = *(const short8*)(rrow + (ks - 4) * 32 + quad * 8);
        short8 bfrag = bp[(ks * 8 + wave) * 64];
        acc1 = __builtin_amdgcn_mfma_f32_16x16x32_bf16(afrag, bfrag, acc1, 0, 0, 0);
    }

    int col = wave * 16 + row16;
    if (!CHAIN) {
        float bv = bias1[col];
        #pragma unroll
        for (int r = 0; r < 4; ++r) {
            int row = nodeBase + quad * 4 + r;
            if (row < N_NODES) {
                float v = fmaxf(acc1[r] + bv, 0.f);
                h_out[(size_t)row * 128 + col] = f2bf(v);
            }
        }
    } else {
        __syncthreads();   // all A-tile reads done before overwrite
        float bv = bias1[col];
        #pragma unroll
        for (int r = 0; r < 4; ++r) {
            float v = fmaxf(acc1[r] + bv, 0.f);
            At[(quad * 4 + r) * 136 + col] = f2bf(v);   // h2 tile
        }
        __syncthreads();

        const short8* bpz = (const short8*)Bpkz + lane;
        f32x4 acc2 = {0.f, 0.f, 0.f, 0.f};
        #pragma unroll
        for (int ks = 0; ks < 4; ++ks) {
            short8 afrag = *(const short8*)&At[row16 * 136 + ks * 32 + quad * 8];
            short8 bfrag = bpz[(ks * 8 + wave) * 64];
            acc2 = __builtin_amdgcn_mfma_f32_16x16x32_bf16(afrag, bfrag, acc2, 0, 0, 0);
        }

        #pragma unroll
        for (int r = 0; r < 4; ++r) {
            int row = nodeBase + quad * 4 + r;
            if (row < N_NODES) {
                if (col < 64) z_bf[(size_t)row * 64 + col] = f2bf(acc2[r]);
                else          r_f32[(size_t)row * 64 + (col - 64)] = acc2[r] + bias2[col - 64];
            }
        }
    }
}

// ---------------- final: fat gather (8 edges/load) + log_softmax ----------------
// 64-dim rows = 8 uint4; chunk = lane&7, esel = lane>>3.
__global__ void final_agg_softmax(const uint4* __restrict__ zb,
                                  const float* __restrict__ r_f32,
                                  const int* __restrict__ rowstart,
                                  const int* __restrict__ csr_src,
                                  float* __restrict__ out) {
    int node = blockIdx.x * 4 + (threadIdx.x >> 6);
    int lane = threadIdx.x & 63;
    if (node >= N_NODES) return;
    int s0 = rowstart[node], s1 = rowstart[node + 1];
    int chunk = lane & 7, esel = lane >> 3;
    float acc[8];
    #pragma unroll
    for (int k = 0; k < 8; ++k) acc[k] = 0.f;
    for (int b = s0; b < s1; b += 64) {
        int m = min(64, s1 - b);
        int idx = (lane < m) ? csr_src[b + lane] : 0;
        int j = 0;
        for (; j + 32 <= m; j += 32) {
            int i0 = __shfl(idx, j + esel, 64);
            int i1 = __shfl(idx, j + 8 + esel, 64);
            int i2 = __shfl(idx, j + 16 + esel, 64);
            int i3 = __shfl(idx, j + 24 + esel, 64);
            uint4 v0 = zb[(size_t)i0 * 8 + chunk];
            uint4 v1 = zb[(size_t)i1 * 8 + chunk];
            uint4 v2 = zb[(size_t)i2 * 8 + chunk];
            uint4 v3 = zb[(size_t)i3 * 8 + chunk];
            acc[0] += (bflo(v0.x) + bflo(v1.x)) + (bflo(v2.x) + bflo(v3.x));
            acc[1] += (bfhi(v0.x) + bfhi(v1.x)) + (bfhi(v2.x) + bfhi(v3.x));
            acc[2] += (bflo(v0.y) + bflo(v1.y)) + (bflo(v2.y) + bflo(v3.y));
            acc[3] += (bfhi(v0.y) + bfhi(v1.y)) + (bfhi(v2.y) + bfhi(v3.y));
            acc[4] += (bflo(v0.z) + bflo(v1.z)) + (bflo(v2.z) + bflo(v3.z));
            acc[5] += (bfhi(v0.z) + bfhi(v1.z)) + (bfhi(v2.z) + bfhi(v3.z));
            acc[6] += (bflo(v0.w) + bflo(v1.w)) + (bflo(v2.w) + bflo(v3.w));
            acc[7] += (bfhi(v0.w) + bfhi(v1.w)) + (bfhi(v2.w) + bfhi(v3.w));
        }
        for (; j < m; j += 8) {
            int e = j + esel;
            int s = __shfl(idx, min(e, m - 1), 64);
            if (e < m) {
                uint4 v = zb[(size_t)s * 8 + chunk];
                acc[0] += bflo(v.x); acc[1] += bfhi(v.x);
                acc[2] += bflo(v.y); acc[3] += bfhi(v.y);
                acc[4] += bflo(v.z); acc[5] += bfhi(v.z);
                acc[6] += bflo(v.w); acc[7] += bfhi(v.w);
            }
        }
    }
    float inv = 1.0f / fmaxf((float)(s1 - s0), 1.0f);
    #pragma unroll
    for (int k = 0; k < 8; ++k) {
        acc[k] += __shfl_xor(acc[k], 8, 64);
        acc[k] += __shfl_xor(acc[k], 16, 64);
        acc[k] += __shfl_xor(acc[k], 32, 64);
    }
    const float4* rp = (const float4*)(r_f32 + (size_t)node * 64 + chunk * 8);
    float4 r0 = rp[0], r1 = rp[1];
    float h[8];
    h[0] = acc[0] * inv + r0.x; h[1] = acc[1] * inv + r0.y;
    h[2] = acc[2] * inv + r0.z; h[3] = acc[3] * inv + r0.w;
    h[4] = acc[4] * inv + r1.x; h[5] = acc[5] * inv + r1.y;
    h[6] = acc[6] * inv + r1.z; h[7] = acc[7] * inv + r1.w;
    float mx = h[0];
    #pragma unroll
    for (int k = 1; k < 8; ++k) mx = fmaxf(mx, h[k]);
    mx = fmaxf(mx, __shfl_xor(mx, 1, 64));
    mx = fmaxf(mx, __shfl_xor(mx, 2, 64));
    mx = fmaxf(mx, __shfl_xor(mx, 4, 64));
    float s = 0.f;
    #pragma unroll
    for (int k = 0; k < 8; ++k) s += expf(h[k] - mx);
    s += __shfl_xor(s, 1, 64);
    s += __shfl_xor(s, 2, 64);
    s += __shfl_xor(s, 4, 64);
    float lse = mx + logf(s);
    if (lane < 8) {
        float4* o0 = (float4*)(out + (size_t)node * 64 + chunk * 8);
        float4* o1 = (float4*)(out + (size_t)N_NODES * 64 + (size_t)node * 64 + chunk * 8);
        float4 a = {h[0] - lse, h[1] - lse, h[2] - lse, h[3] - lse};
        float4 bq = {h[4] - lse, h[5] - lse, h[6] - lse, h[7] - lse};
        o0[0] = a; o0[1] = bq;
        float4 c = {h[0], h[1], h[2], h[3]};
        float4 d = {h[4], h[5], h[6], h[7]};
        o1[0] = c; o1[1] = d;
    }
}

extern "C" void kernel_launch(void* const* d_in, const int* in_sizes, int n_in,
                              void* d_out, int out_size, void* d_ws, size_t ws_size,
                              hipStream_t stream) {
    const float* x  = (const float*)d_in[0];
    const int* ei   = (const int*)d_in[1];
    const float* Wl0 = (const float*)d_in[2];
    const float* Wr0 = (const float*)d_in[3];
    const float* b0  = (const float*)d_in[4];
    const float* Wl1 = (const float*)d_in[5];
    const float* Wr1 = (const float*)d_in[6];
    const float* b1  = (const float*)d_in[7];
    const float* Wl2 = (const float*)d_in[8];
    const float* Wr2 = (const float*)d_in[9];
    const float* b2  = (const float*)d_in[10];
    float* out = (float*)d_out;

    char* ws = (char*)d_ws;
    int* cnt      = (int*)(ws + 0x000000);
    int* rowstart = (int*)(ws + 0x040000);
    int* cursor   = (int*)(ws + 0x080000);
    int* csr_src  = (int*)(ws + 0x100000);            // 3.2 MB
    ushort_t* pk0 = (ushort_t*)(ws + 0x420000);       // 64 KB
    ushort_t* pk1 = (ushort_t*)(ws + 0x440000);       // 64 KB
    ushort_t* pkz = (ushort_t*)(ws + 0x460000);       // 32 KB
    ushort_t* x_bf = (ushort_t*)(ws + 0x0500000);     // 12.8 MB; dead after layer0
    ushort_t* h1   = (ushort_t*)(ws + 0x1F00000);     // 12.8 MB
    ushort_t* z_bf = (ushort_t*)(ws + 0x1200000);     // 6.4 MB
    float*    r_f32 = (float*)  (ws + 0x0500000);     // 12.8 MB, aliases x_bf (dead)

    // ---- prep: cvt + weight packs + zero cnt (one kernel) ----
    prep<<<6619, 256, 0, stream>>>(x, (uint_t*)x_bf, Wl0, Wr0, Wl1, Wr1, Wl2, Wr2,
                                   pk0, pk1, pkz, cnt);

    // ---- CSR build: count -> scan(1 kernel) -> fill ----
    count_edges_mp<<<1024, 256, 0, stream>>>(ei, cnt);
    scan_all<<<SCAN_BLOCKS, 256, 0, stream>>>(cnt, rowstart, cursor);
    fill_csr_mp<<<1024, 256, 0, stream>>>(ei, cursor, csr_src);

    // ---- layer 0 fused (16 nodes/block, 8 waves): x -> h1 ----
    layer_fused<false><<<3125, 512, 0, stream>>>(
        (const uint4*)x_bf, x_bf, rowstart, csr_src, pk0, b0,
        nullptr, nullptr, h1, nullptr, nullptr);

    // ---- layers 1+2 fused: h1 -> (z, r); h2 never leaves LDS ----
    layer_fused<true><<<3125, 512, 0, stream>>>(
        (const uint4*)h1, h1, rowstart, csr_src, pk1, b1,
        pkz, b2, nullptr, z_bf, r_f32);

    // ---- final gather (8 edges/load) + log_softmax -> d_out ----
    final_agg_softmax<<<12500, 256, 0, stream>>>((const uint4*)z_bf, r_f32,
                                                 rowstart, csr_src, out);
}